// Round 14
// baseline (275.985 us; speedup 1.0000x reference)
//
#include <hip/hip_runtime.h>

#define N_NODES 50000
#define N_EDGES 800000
#define DIM 128
#define N_GRAPHS 256
#define N_CLS 10
#define BN_EPSV 1e-5f
#define CAP 64
#define RSIZE 6250  // N_NODES / 8
#define NBLK32 ((N_NODES + 31) / 32)
#define ZROW N_NODES  // index of the all-zero feature row

typedef __attribute__((ext_vector_type(8))) short short8;
typedef __attribute__((ext_vector_type(4))) float f32x4;

__device__ __forceinline__ float bf2f(short u) {
  return __uint_as_float(((unsigned)(unsigned short)u) << 16);
}
__device__ __forceinline__ unsigned short f2bf(float f) {
  unsigned u = __float_as_uint(f);
  unsigned r = (u + 0x7FFFu + ((u >> 16) & 1u)) >> 16;
  return (unsigned short)r;
}
// XOR swizzle: spreads row-major [32][128]-bf16 rows across banks for ds_read_b128
__device__ __forceinline__ int swz(int row, int bytecol) {
  return row * 256 + (bytecol ^ ((row & 7) << 4));
}

// ---------------- prep: cvt_w | cvt_x | bounds+cnt-zero | zero-rows ---------

__global__ __launch_bounds__(256) void prep_kernel(
    const float* __restrict__ x, ushort* __restrict__ xb,
    const float* __restrict__ w0, const float* __restrict__ w1,
    const float* __restrict__ w2, const float* __restrict__ w3,
    const float* __restrict__ w4, const float* __restrict__ w5,
    ushort* __restrict__ wt, const int* __restrict__ batch,
    int* __restrict__ gstart, int* __restrict__ cnt,
    ushort* __restrict__ z0, ushort* __restrict__ z1) {
  int bid = blockIdx.x, tid = threadIdx.x;
  if (bid < 384) {
    // W (fan_in x fan_out) fp32 -> W^T bf16, 6 matrices
    int m = bid >> 6;
    const float* w = m == 0 ? w0 : m == 1 ? w1 : m == 2 ? w2 : m == 3 ? w3
                                                         : m == 4 ? w4 : w5;
    int idx = (bid & 63) * 256 + tid;
    int k = idx >> 7, n = idx & 127;
    wt[m * 16384 + n * 128 + k] = f2bf(w[idx]);
  } else if (bid < 384 + 2048) {
    const int tot = N_NODES * DIM / 4;
    int i = (bid - 384) * 256 + tid;
    for (; i < tot; i += 2048 * 256) {
      float4 v = ((const float4*)x)[i];
      ushort4 o;
      o.x = f2bf(v.x); o.y = f2bf(v.y); o.z = f2bf(v.z); o.w = f2bf(v.w);
      ((ushort4*)xb)[i] = o;
    }
  } else if (bid < 384 + 2048 + 196) {
    int i = (bid - (384 + 2048)) * 256 + tid;
    if (i < N_NODES) {
      cnt[i] = 0;
      int b = batch[i];
      int prev = (i == 0) ? -1 : batch[i - 1];
      for (int g = prev + 1; g <= b; g++) gstart[g] = i;
      if (i == N_NODES - 1)
        for (int g = b + 1; g <= N_GRAPHS; g++) gstart[g] = N_NODES;
    }
  } else {
    if (tid < DIM) {
      z0[(size_t)ZROW * DIM + tid] = 0;
      z1[(size_t)ZROW * DIM + tid] = 0;
    }
  }
}

// ---------------- CSR build: XCD-affine range partition ---------------------

__global__ __launch_bounds__(256) void fill_kernel(
    const int* __restrict__ src, const int* __restrict__ dst,
    int* __restrict__ cnt, ushort* __restrict__ csr) {
  int cls = blockIdx.x & 7;
  int lo = cls * RSIZE;
  int hi = lo + RSIZE;
  int i = (blockIdx.x >> 3) * blockDim.x + threadIdx.x;
  int stride = (gridDim.x >> 3) * blockDim.x;
  for (; i < N_EDGES; i += stride) {
    int d = dst[i];
    if (d >= lo && d < hi) {
      int p = atomicAdd(&cnt[d], 1);
      if (p < CAP) csr[(size_t)d * CAP + p] = (ushort)src[i];
    }
  }
}

// ---------------- fused layer: pair-pipelined gather -> LDS -> 2x MFMA GEMM -
// 256 thr / 4 waves / 32 nodes / 20KB LDS, __launch_bounds__(256,4):
// VGPR cap 128 (was 64) so Phase A can keep EIGHT 256B feature rows in
// flight per wave — two nodes processed simultaneously, all 8 loads issued
// before any accumulation. Invalid slots redirect to the L2-hot zero row
// (no garbage traffic). BN sc/sh staged in phase-C-dead sums/sqs LDS.

template <bool FIRST>
__global__ __launch_bounds__(256, 4) void layer_kernel(
    const ushort* __restrict__ xin, const int* __restrict__ cnt,
    const ushort* __restrict__ csr, const float* __restrict__ pstats,
    const float* __restrict__ pgamma, const float* __restrict__ pbeta,
    const float* __restrict__ epsp, int layer,
    const ushort* __restrict__ W1T, const float* __restrict__ b1,
    const ushort* __restrict__ W2T, const float* __restrict__ b2,
    ushort* __restrict__ out, float* __restrict__ bstat) {
  __shared__ __align__(16) ushort As[32 * DIM];
  __shared__ __align__(16) ushort H1[32 * DIM];
  __shared__ float sums[4 * DIM];
  __shared__ float sqs[4 * DIM];
  int tid = threadIdx.x;
  int w4 = tid >> 6;       // wave 0..3
  int l = tid & 63, li = l & 15, lg = l >> 4;
  int row0 = blockIdx.x * 32;
  float epv = 1.0f + epsp[layer];
  if (!FIRST) {
    // stage BN affine (sc, sh) into phase-C-dead LDS
    if (tid < DIM) {
      const float invN = 1.0f / N_NODES;
      float mu = pstats[tid] * invN;
      float var = fmaxf(pstats[DIM + tid] * invN - mu * mu, 0.f);
      float sc = pgamma[tid] * rsqrtf(var + BN_EPSV);
      sums[tid] = sc;
      sqs[tid] = pbeta[tid] - mu * sc;
    }
    __syncthreads();
  }
  // ---- Phase A: pair-pipelined gather (8 feature rows in flight/wave) ----
#pragma unroll
  for (int np = 0; np < 4; np++) {
    int nlA = w4 * 8 + np * 2, nlB = nlA + 1;
    int nodeA = row0 + nlA, nodeB = row0 + nlB;
    int vA = nodeA < N_NODES, vB = nodeB < N_NODES;
    int ncA = vA ? nodeA : 0, ncB = vB ? nodeB : 0;
    int dA = cnt[ncA];
    dA = dA < CAP ? dA : CAP;
    dA = vA ? dA : 0;
    int dB = cnt[ncB];
    dB = dB < CAP ? dB : CAP;
    dB = vB ? dB : 0;
    const ushort* nbA = csr + (size_t)ncA * CAP;
    const ushort* nbB = csr + (size_t)ncB * CAP;
    float avA[8], avB[8];
#pragma unroll
    for (int j = 0; j < 8; j++) { avA[j] = 0.f; avB[j] = 0.f; }
    if (lg == 0) {
      short8 sA = *(const short8*)(xin + (size_t)ncA * DIM + li * 8);
      short8 sB = *(const short8*)(xin + (size_t)ncB * DIM + li * 8);
      float mA = vA ? epv : 0.f, mB = vB ? epv : 0.f;
#pragma unroll
      for (int j = 0; j < 8; j++) {
        avA[j] = mA * bf2f(sA[j]);
        avB[j] = mB * bf2f(sB[j]);
      }
    }
    int dmax = dA > dB ? dA : dB;
    int nbat = (dmax + 15) >> 4;
    for (int b = 0; b < nbat; b++) {
      int i0 = b * 16 + lg, i1 = i0 + 4, i2 = i0 + 8, i3 = i0 + 12;
      // csr reads clamp to slot 0 (safe); invalid slots -> zero row
      int rA0 = nbA[i0 < dA ? i0 : 0], rA1 = nbA[i1 < dA ? i1 : 0];
      int rA2 = nbA[i2 < dA ? i2 : 0], rA3 = nbA[i3 < dA ? i3 : 0];
      int rB0 = nbB[i0 < dB ? i0 : 0], rB1 = nbB[i1 < dB ? i1 : 0];
      int rB2 = nbB[i2 < dB ? i2 : 0], rB3 = nbB[i3 < dB ? i3 : 0];
      int jA0 = i0 < dA ? rA0 : ZROW, jA1 = i1 < dA ? rA1 : ZROW;
      int jA2 = i2 < dA ? rA2 : ZROW, jA3 = i3 < dA ? rA3 : ZROW;
      int jB0 = i0 < dB ? rB0 : ZROW, jB1 = i1 < dB ? rB1 : ZROW;
      int jB2 = i2 < dB ? rB2 : ZROW, jB3 = i3 < dB ? rB3 : ZROW;
      short8 fA0 = *(const short8*)(xin + (size_t)jA0 * DIM + li * 8);
      short8 fA1 = *(const short8*)(xin + (size_t)jA1 * DIM + li * 8);
      short8 fA2 = *(const short8*)(xin + (size_t)jA2 * DIM + li * 8);
      short8 fA3 = *(const short8*)(xin + (size_t)jA3 * DIM + li * 8);
      short8 fB0 = *(const short8*)(xin + (size_t)jB0 * DIM + li * 8);
      short8 fB1 = *(const short8*)(xin + (size_t)jB1 * DIM + li * 8);
      short8 fB2 = *(const short8*)(xin + (size_t)jB2 * DIM + li * 8);
      short8 fB3 = *(const short8*)(xin + (size_t)jB3 * DIM + li * 8);
#pragma unroll
      for (int j = 0; j < 8; j++) {
        avA[j] += (bf2f(fA0[j]) + bf2f(fA1[j])) + (bf2f(fA2[j]) + bf2f(fA3[j]));
        avB[j] += (bf2f(fB0[j]) + bf2f(fB1[j])) + (bf2f(fB2[j]) + bf2f(fB3[j]));
      }
    }
#pragma unroll
    for (int j = 0; j < 8; j++) {
      avA[j] += __shfl_xor(avA[j], 16, 64);
      avA[j] += __shfl_xor(avA[j], 32, 64);
      avB[j] += __shfl_xor(avB[j], 16, 64);
      avB[j] += __shfl_xor(avB[j], 32, 64);
    }
    if (lg == 0) {
      if (!FIRST) {
        float coA = epv + (float)dA, coB = epv + (float)dB;
#pragma unroll
        for (int j = 0; j < 8; j++) {
          float sc = sums[li * 8 + j], sh = sqs[li * 8 + j];
          avA[j] = sc * avA[j] + coA * sh;
          avB[j] = sc * avB[j] + coB * sh;
        }
      }
      short8 uA, uB;
#pragma unroll
      for (int j = 0; j < 8; j++) {
        uA[j] = (short)f2bf(avA[j]);
        uB[j] = (short)f2bf(avB[j]);
      }
      *(short8*)((char*)As + swz(nlA, li * 16)) = uA;
      *(short8*)((char*)As + swz(nlB, li * 16)) = uB;
    }
  }
  __syncthreads();
  // ---- Phase B: H1[rows wg][cts ch*4..] = relu(As @ W1 + b1) ----
  int wg = w4 >> 1;        // row group (16 rows each, 0..1)
  int ch = w4 & 1;         // column half: cts [ch*4, ch*4+3]
  {
    f32x4 acc[4] = {};
    short8 af[4];
#pragma unroll
    for (int ks = 0; ks < 4; ks++)
      af[ks] = *(const short8*)((char*)As + swz(16 * wg + li, ks * 64 + lg * 16));
#pragma unroll
    for (int ct4 = 0; ct4 < 4; ct4++) {
      int ct = ch * 4 + ct4;
      const char* wp = (const char*)W1T + (ct * 16 + li) * 256 + lg * 16;
#pragma unroll
      for (int ks = 0; ks < 4; ks++) {
        short8 bf = *(const short8*)(wp + ks * 64);
        acc[ct4] = __builtin_amdgcn_mfma_f32_16x16x32_bf16(af[ks], bf, acc[ct4], 0, 0, 0);
      }
    }
#pragma unroll
    for (int ct4 = 0; ct4 < 4; ct4++) {
      int ct = ch * 4 + ct4;
      float bv = b1[ct * 16 + li];
#pragma unroll
      for (int r = 0; r < 4; r++) {
        int row = 16 * wg + lg * 4 + r;
        *(ushort*)((char*)H1 + swz(row, (ct * 16 + li) * 2)) =
            f2bf(fmaxf(acc[ct4][r] + bv, 0.f));
      }
    }
  }
  __syncthreads();
  // ---- Phase C: h2 = relu(H1 @ W2 + b2) -> staged LDS + partial stats ----
  float ss[4] = {0, 0, 0, 0}, sq[4] = {0, 0, 0, 0};
  {
    f32x4 acc[4] = {};
    short8 af[4];
#pragma unroll
    for (int ks = 0; ks < 4; ks++)
      af[ks] = *(const short8*)((char*)H1 + swz(16 * wg + li, ks * 64 + lg * 16));
#pragma unroll
    for (int ct4 = 0; ct4 < 4; ct4++) {
      int ct = ch * 4 + ct4;
      const char* wp = (const char*)W2T + (ct * 16 + li) * 256 + lg * 16;
#pragma unroll
      for (int ks = 0; ks < 4; ks++) {
        short8 bf = *(const short8*)(wp + ks * 64);
        acc[ct4] = __builtin_amdgcn_mfma_f32_16x16x32_bf16(af[ks], bf, acc[ct4], 0, 0, 0);
      }
    }
#pragma unroll
    for (int ct4 = 0; ct4 < 4; ct4++) {
      int ct = ch * 4 + ct4;
      float bv = b2[ct * 16 + li];
#pragma unroll
      for (int r = 0; r < 4; r++) {
        int row = 16 * wg + lg * 4 + r;
        float v = fmaxf(acc[ct4][r] + bv, 0.f);
        *(ushort*)((char*)As + swz(row, (ct * 16 + li) * 2)) = f2bf(v);
        float vm = (row0 + row < N_NODES) ? v : 0.f;
        ss[ct4] += vm;
        sq[ct4] += vm * vm;
      }
    }
  }
#pragma unroll
  for (int ct4 = 0; ct4 < 4; ct4++) {
    ss[ct4] += __shfl_xor(ss[ct4], 16, 64);
    ss[ct4] += __shfl_xor(ss[ct4], 32, 64);
    sq[ct4] += __shfl_xor(sq[ct4], 16, 64);
    sq[ct4] += __shfl_xor(sq[ct4], 32, 64);
  }
  if (l < 16) {
#pragma unroll
    for (int ct4 = 0; ct4 < 4; ct4++) {
      sums[w4 * DIM + (ch * 4 + ct4) * 16 + l] = ss[ct4];
      sqs[w4 * DIM + (ch * 4 + ct4) * 16 + l] = sq[ct4];
      sums[w4 * DIM + ((1 - ch) * 4 + ct4) * 16 + l] = 0.f;
      sqs[w4 * DIM + ((1 - ch) * 4 + ct4) * 16 + l] = 0.f;
    }
  }
  __syncthreads();
  // coalesced copy-out of staged h2
  for (int t = tid; t < 512; t += 256) {
    int row = t >> 4, chunk = t & 15;
    int grow = row0 + row;
    if (grow < N_NODES) {
      short8 v = *(const short8*)((char*)As + swz(row, chunk * 16));
      *(short8*)(out + (size_t)grow * DIM + chunk * 8) = v;
    }
  }
  if (tid < DIM) {
    float t1 = 0.f, t2 = 0.f;
#pragma unroll
    for (int g = 0; g < 4; g++) {
      t1 += sums[g * DIM + tid];
      t2 += sqs[g * DIM + tid];
    }
    bstat[(size_t)blockIdx.x * DIM + tid] = t1;
    bstat[((size_t)NBLK32 + blockIdx.x) * DIM + tid] = t2;
  }
}

// ---------------- stats reduce: 256 cols (sum | sumsq), shuffle-reduce ------

__global__ __launch_bounds__(64) void stats_reduce_kernel(
    const float* __restrict__ bstat, float* __restrict__ stats) {
  int c = blockIdx.x;  // 0..127 -> col sums; 128..255 -> col sumsqs
  int t = threadIdx.x;
  const float* src = bstat + (c < DIM ? 0 : (size_t)NBLK32 * DIM) + (c & (DIM - 1));
  float a = 0.f;
  for (int b = t; b < NBLK32; b += 64) a += src[(size_t)b * DIM];
#pragma unroll
  for (int m = 32; m >= 1; m >>= 1) a += __shfl_xor(a, m, 64);
  if (t == 0) stats[c] = a;
}

// ---------------- pooling: one block per graph, contiguous rows, no atomics -

__global__ __launch_bounds__(128) void pool2_kernel(const ushort* __restrict__ h,
    const int* __restrict__ gstart, float* __restrict__ pool) {
  int g = blockIdx.x, t = threadIdx.x;
  int s = gstart[g], e = gstart[g + 1];
  float a0 = 0.f, a1 = 0.f, a2 = 0.f, a3 = 0.f;
  int i = s;
  for (; i + 3 < e; i += 4) {
    a0 += bf2f((short)h[(size_t)(i + 0) * DIM + t]);
    a1 += bf2f((short)h[(size_t)(i + 1) * DIM + t]);
    a2 += bf2f((short)h[(size_t)(i + 2) * DIM + t]);
    a3 += bf2f((short)h[(size_t)(i + 3) * DIM + t]);
  }
  for (; i < e; i++) a0 += bf2f((short)h[(size_t)i * DIM + t]);
  float cn = (float)(e - s);
  if (cn < 1.f) cn = 1.f;
  pool[g * DIM + t] = ((a0 + a1) + (a2 + a3)) / cn;
}

// ---------------- final: BN affine (layer 3) + MLP + log_softmax -----------

__global__ __launch_bounds__(128) void final_kernel(const float* __restrict__ pool,
    const float* __restrict__ stats3,
    const float* __restrict__ gamma3, const float* __restrict__ beta3,
    const float* __restrict__ lw1, const float* __restrict__ lb1,
    const float* __restrict__ lw2, const float* __restrict__ lb2,
    float* __restrict__ out) {
  int g = blockIdx.x, t = threadIdx.x;
  __shared__ float p[DIM];
  __shared__ float part[2];
  __shared__ float z2[N_CLS];
  const float invN = 1.0f / N_NODES;
  float mu = stats3[t] * invN;
  float var = fmaxf(stats3[DIM + t] * invN - mu * mu, 0.f);
  float sc = gamma3[t] * rsqrtf(var + BN_EPSV);
  float sh = beta3[t] - mu * sc;
  p[t] = sc * pool[g * DIM + t] + sh;
  __syncthreads();
  float acc = lb1[t];
  for (int k = 0; k < DIM; k++) acc += p[k] * lw1[k * DIM + t];
  acc = fmaxf(acc, 0.f);
  for (int c = 0; c < N_CLS; c++) {
    float v = acc * lw2[t * N_CLS + c];
#pragma unroll
    for (int m = 32; m >= 1; m >>= 1) v += __shfl_xor(v, m, 64);
    if ((t & 63) == 0) part[t >> 6] = v;
    __syncthreads();
    if (t == 0) z2[c] = part[0] + part[1] + lb2[c];
    __syncthreads();
  }
  if (t == 0) {
    float mx = -1e30f;
    for (int c = 0; c < N_CLS; c++) mx = fmaxf(mx, z2[c]);
    float sum = 0.f;
    for (int c = 0; c < N_CLS; c++) sum += expf(z2[c] - mx);
    float lse = mx + logf(sum);
    for (int c = 0; c < N_CLS; c++) out[g * N_CLS + c] = z2[c] - lse;
  }
}

// ---------------- launch ----------------

extern "C" void kernel_launch(void* const* d_in, const int* in_sizes, int n_in,
                              void* d_out, int out_size, void* d_ws, size_t ws_size,
                              hipStream_t stream) {
  const float* x = (const float*)d_in[0];
  const int* edge = (const int*)d_in[1];
  const int* batch = (const int*)d_in[2];
  const float *w[3][2], *bv[3][2], *gam[3], *bet[3];
  int idx = 3;
  for (int l = 0; l < 3; l++) {
    w[l][0] = (const float*)d_in[idx++]; bv[l][0] = (const float*)d_in[idx++];
    w[l][1] = (const float*)d_in[idx++]; bv[l][1] = (const float*)d_in[idx++];
    gam[l] = (const float*)d_in[idx++];  bet[l] = (const float*)d_in[idx++];
  }
  const float* eps = (const float*)d_in[idx++];
  const float* lw1 = (const float*)d_in[idx++];
  const float* lb1 = (const float*)d_in[idx++];
  const float* lw2 = (const float*)d_in[idx++];
  const float* lb2 = (const float*)d_in[idx++];

  char* ws = (char*)d_ws;
  size_t off_b = 0;
  auto alloc = [&](size_t b) -> char* {
    char* p = ws + off_b;
    off_b += (b + 255) & ~(size_t)255;
    return p;
  };
  int* cnt = (int*)alloc((size_t)N_NODES * 4);
  ushort* csr = (ushort*)alloc((size_t)N_NODES * CAP * 2);
  ushort* P0 = (ushort*)alloc((size_t)(N_NODES + 1) * DIM * 2);  // xb / h layers
  ushort* P1 = (ushort*)alloc((size_t)(N_NODES + 1) * DIM * 2);
  ushort* wt = (ushort*)alloc((size_t)6 * 16384 * 2);
  float* stats = (float*)alloc(3 * 2 * DIM * 4);
  float* pool = (float*)alloc((size_t)N_GRAPHS * DIM * 4);
  int* gstart = (int*)alloc((size_t)(N_GRAPHS + 1) * 4);
  float* bstat = (float*)alloc((size_t)2 * NBLK32 * DIM * 4);

  const int* srcp = edge;
  const int* dstp = edge + N_EDGES;
  // prep: cvt_w (384) | cvt_x (2048) | bounds+cnt0 (196) | zero-rows (1)
  prep_kernel<<<384 + 2048 + 196 + 1, 256, 0, stream>>>(
      x, P0, w[0][0], w[0][1], w[1][0], w[1][1], w[2][0], w[2][1], wt,
      batch, gstart, cnt, P0, P1);
  fill_kernel<<<2048, 256, 0, stream>>>(srcp, dstp, cnt, csr);

  // L1: layer(P0)->P1
  layer_kernel<true><<<NBLK32, 256, 0, stream>>>(
      P0, cnt, csr, nullptr, nullptr, nullptr, eps, 0,
      wt + 0 * 16384, bv[0][0], wt + 1 * 16384, bv[0][1], P1, bstat);
  stats_reduce_kernel<<<256, 64, 0, stream>>>(bstat, stats);
  // L2: layer(P1, fold s0)->P0
  layer_kernel<false><<<NBLK32, 256, 0, stream>>>(
      P1, cnt, csr, stats, gam[0], bet[0], eps, 1,
      wt + 2 * 16384, bv[1][0], wt + 3 * 16384, bv[1][1], P0, bstat);
  stats_reduce_kernel<<<256, 64, 0, stream>>>(bstat, stats + 2 * DIM);
  // L3: layer(P0, fold s1)->P1
  layer_kernel<false><<<NBLK32, 256, 0, stream>>>(
      P0, cnt, csr, stats + 2 * DIM, gam[1], bet[1], eps, 2,
      wt + 4 * 16384, bv[2][0], wt + 5 * 16384, bv[2][1], P1, bstat);
  stats_reduce_kernel<<<256, 64, 0, stream>>>(bstat, stats + 4 * DIM);

  pool2_kernel<<<N_GRAPHS, 128, 0, stream>>>(P1, gstart, pool);
  final_kernel<<<N_GRAPHS, 128, 0, stream>>>(pool, stats + 4 * DIM,
                                             gam[2], bet[2], lw1, lb1, lw2, lb2,
                                             (float*)d_out);
}